// Round 15
// baseline (286.868 us; speedup 1.0000x reference)
//
#include <hip/hip_runtime.h>
#include <hip/hip_bf16.h>

#define SEQ 4096
#define DMODEL 512
#define HEADS 8
#define DK 64
#define BATCH 2
#define MTOT (BATCH * SEQ)     // 8192
#define NBH (BATCH * HEADS)    // 16

typedef __attribute__((ext_vector_type(8))) short bh8;    // 8 bf16 (4 VGPR)
typedef __attribute__((ext_vector_type(4))) float f4;
typedef __attribute__((ext_vector_type(16))) float f16x;
typedef __attribute__((ext_vector_type(2))) float f2;

union uf { f16x v; f2 h[8]; };

#define MFMA(a, b, c)   __builtin_amdgcn_mfma_f32_16x16x32_bf16(a, b, c, 0, 0, 0)
#define MFMA32(a, b, c) __builtin_amdgcn_mfma_f32_32x32x16_bf16(a, b, c, 0, 0, 0)
#define GLL16(g, l) __builtin_amdgcn_global_load_lds( \
    (const __attribute__((address_space(1))) void*)(g), \
    (__attribute__((address_space(3))) void*)(l), 16, 0, 0)

__device__ __forceinline__ unsigned short f2b(float f) {
    union { float f; unsigned u; } v; v.f = f;
    unsigned r = v.u + 0x7fff + ((v.u >> 16) & 1);   // RNE, finite inputs
    return (unsigned short)(r >> 16);
}
__device__ __forceinline__ float lo2f(unsigned u) {
    union { unsigned u; float f; } v; v.u = u << 16; return v.f;
}
__device__ __forceinline__ float hi2f(unsigned u) {
    union { unsigned u; float f; } v; v.u = u & 0xffff0000u; return v.f;
}

__device__ __forceinline__ unsigned cvtpk(float lo, float hi) {
    unsigned r;
    asm("v_cvt_pk_bf16_f32 %0, %1, %2" : "=v"(r) : "v"(lo), "v"(hi));
    return r;
}
__device__ __forceinline__ void plswap(unsigned& a, unsigned& b) {
    asm("v_permlane32_swap_b32 %0, %1" : "+v"(a), "+v"(b));
}
__device__ __forceinline__ float wave_max_pair(float x) {
    float b = x; asm("" : "+v"(b));
    float a = x;
    asm("v_permlane32_swap_b32 %0, %1" : "+v"(a), "+v"(b));
    return fmaxf(a, b);
}
__device__ __forceinline__ float wave_sum_pair(float x) {
    float b = x; asm("" : "+v"(b));
    float a = x;
    asm("v_permlane32_swap_b32 %0, %1" : "+v"(a), "+v"(b));
    return a + b;
}
__device__ __forceinline__ f2 pk_add(f2 a, f2 b) {
    f2 d; asm("v_pk_add_f32 %0, %1, %2" : "=v"(d) : "v"(a), "v"(b)); return d;
}
__device__ __forceinline__ f2 pk_mul(f2 a, f2 b) {
    f2 d; asm("v_pk_mul_f32 %0, %1, %2" : "=v"(d) : "v"(a), "v"(b)); return d;
}
__device__ __forceinline__ float max3f(float a, float b, float c) {
    float d; asm("v_max3_f32 %0, %1, %2, %3" : "=v"(d) : "v"(a), "v"(b), "v"(c));
    return d;
}

// ---------------------------------------------------------------------------
// fp32 -> bf16 conversion: [x | wq | wk | wv | wo]
// ---------------------------------------------------------------------------
__global__ __launch_bounds__(256) void convert_k(
    const float* __restrict__ x, const float* __restrict__ wq,
    const float* __restrict__ wk, const float* __restrict__ wv,
    const float* __restrict__ wo, unsigned short* __restrict__ dst)
{
    const size_t i = ((size_t)blockIdx.x * 256 + threadIdx.x) * 4;
    const float* s; size_t o;
    if (i < 4194304u)                 { s = x;  o = i; }
    else if (i < 4194304u + 262144u)  { s = wq; o = i - 4194304u; }
    else if (i < 4194304u + 524288u)  { s = wk; o = i - (4194304u + 262144u); }
    else if (i < 4194304u + 786432u)  { s = wv; o = i - (4194304u + 524288u); }
    else                              { s = wo; o = i - (4194304u + 786432u); }
    float4 v = *(const float4*)(s + o);
    ushort4 u; u.x = f2b(v.x); u.y = f2b(v.y); u.z = f2b(v.z); u.w = f2b(v.w);
    *(ushort4*)(dst + i) = u;
}

// ---------------------------------------------------------------------------
// QKV projection (MFMA, 128x128 tile). Q pre-scaled by 0.125*log2(e) so the
// flash kernel works in exp2 domain (softmax is base-invariant).
// ---------------------------------------------------------------------------
__global__ __launch_bounds__(256) void qkv_gemm_mfma(
    const unsigned short* __restrict__ xb,
    const unsigned short* __restrict__ Wb,
    unsigned short* __restrict__ QKV)
{
    const int z = blockIdx.z;
    const unsigned short* A = xb;
    const unsigned short* B = Wb + (size_t)z * (DMODEL * DMODEL);
    const int m0 = blockIdx.x * 128, n0 = blockIdx.y * 128;
    const int tid = threadIdx.x, w = tid >> 6, l = tid & 63;
    const int wr = w >> 1, wc = w & 1;

    __shared__ __align__(16) unsigned short As[128 * 32];
    __shared__ __align__(16) unsigned short Bs[128 * 32];

    f4 acc[4][4] = {};
    const int lrow = l >> 2, lslot = l & 3;

    for (int k0 = 0; k0 < DMODEL; k0 += 32) {
        __syncthreads();
        #pragma unroll
        for (int j = 0; j < 2; ++j) {
            const int row = w * 32 + j * 16 + lrow;
            const int sw = lslot ^ ((row >> 1) & 3);
            GLL16(A + (size_t)(m0 + row) * DMODEL + k0 + sw * 8,
                  (char*)As + (w * 32 + j * 16) * 64);
            GLL16(B + (size_t)(n0 + row) * DMODEL + k0 + sw * 8,
                  (char*)Bs + (w * 32 + j * 16) * 64);
        }
        __syncthreads();
        bh8 af[4], bg[4];
        #pragma unroll
        for (int mi = 0; mi < 4; ++mi) {
            const int r = wr * 64 + mi * 16 + (l & 15);
            af[mi] = *(const bh8*)((const char*)As + r * 64 +
                                   (((l >> 4) * 16) ^ (((r >> 1) & 3) << 4)));
        }
        #pragma unroll
        for (int ni = 0; ni < 4; ++ni) {
            const int r = wc * 64 + ni * 16 + (l & 15);
            bg[ni] = *(const bh8*)((const char*)Bs + r * 64 +
                                   (((l >> 4) * 16) ^ (((r >> 1) & 3) << 4)));
        }
        #pragma unroll
        for (int mi = 0; mi < 4; ++mi)
            #pragma unroll
            for (int ni = 0; ni < 4; ++ni)
                acc[mi][ni] = MFMA(af[mi], bg[ni], acc[mi][ni]);
    }

    unsigned short* Out = QKV + (size_t)z * ((size_t)NBH * SEQ * DK);
    const float sc = (z == 0) ? 0.18033688011112042f : 1.0f;  // 0.125*log2e
    #pragma unroll
    for (int mi = 0; mi < 4; ++mi) {
        #pragma unroll
        for (int rg = 0; rg < 4; ++rg) {
            const int m = m0 + wr * 64 + mi * 16 + (l >> 4) * 4 + rg;
            const int b = m >> 12, t = m & (SEQ - 1);
            #pragma unroll
            for (int ni = 0; ni < 4; ++ni) {
                const int n = n0 + wc * 64 + ni * 16 + (l & 15);
                const int h = n >> 6, d = n & 63;
                Out[(((size_t)(b * HEADS + h)) * SEQ + t) * DK + d] =
                    f2b(acc[mi][ni][rg] * sc);
            }
        }
    }
}

// ---------------------------------------------------------------------------
// V [bh][t][d] -> Vt [bh][d][t]
// ---------------------------------------------------------------------------
__global__ __launch_bounds__(256) void vtrans(
    const unsigned short* __restrict__ Vh, unsigned short* __restrict__ Vt)
{
    const int bh = blockIdx.y, t0 = blockIdx.x * 64;
    __shared__ unsigned short L[64][72];
    const unsigned short* src = Vh + ((size_t)bh * SEQ + t0) * DK;
    const int r = threadIdx.x >> 3, c8 = (threadIdx.x & 7) * 8;
    #pragma unroll
    for (int it = 0; it < 2; ++it) {
        const int row = r + it * 32;
        ushort4 a = *(const ushort4*)(src + (size_t)row * DK + c8);
        ushort4 b = *(const ushort4*)(src + (size_t)row * DK + c8 + 4);
        L[row][c8 + 0] = a.x; L[row][c8 + 1] = a.y; L[row][c8 + 2] = a.z; L[row][c8 + 3] = a.w;
        L[row][c8 + 4] = b.x; L[row][c8 + 5] = b.y; L[row][c8 + 6] = b.z; L[row][c8 + 7] = b.w;
    }
    __syncthreads();
    unsigned short* dst = Vt + (size_t)bh * DK * SEQ + t0;
    #pragma unroll
    for (int it = 0; it < 2; ++it) {
        const int d = r + it * 32;
        ushort4 a, b;
        a.x = L[c8 + 0][d]; a.y = L[c8 + 1][d]; a.z = L[c8 + 2][d]; a.w = L[c8 + 3][d];
        b.x = L[c8 + 4][d]; b.y = L[c8 + 5][d]; b.z = L[c8 + 6][d]; b.w = L[c8 + 7][d];
        *(ushort4*)(dst + (size_t)d * SEQ + c8) = a;
        *(ushort4*)(dst + (size_t)d * SEQ + c8 + 4) = b;
    }
}

// ---------------------------------------------------------------------------
// Flash attention, BARRIER-FREE: K/V fragments read DIRECTLY from global
// (KV is L2/L3-resident — FETCH counters show 12 MB; staging cache-fit data
// was pure overhead + forced lockstep barriers). Grid 1024 = 16bh x 32qt x
// 2kvp (R12's validated flash-decoding split); 4-wave blocks, single online
// chain per block over kv-2048, kv-tile 64, R8's exact per-tile math.
// LDS = 16 KB, epilogue transpose only. No __syncthreads in the main loop.
// Writes unnormalized partial O + (m,l); merge_k (R12-validated) combines.
// ---------------------------------------------------------------------------
__global__ __launch_bounds__(256) void flash_direct(
    const unsigned short* __restrict__ Qh,   // [NBH][SEQ][DK], pre-scaled
    const unsigned short* __restrict__ Kh,   // [NBH][SEQ][DK]
    const unsigned short* __restrict__ Vtp,  // [NBH][DK][SEQ]
    unsigned short* __restrict__ P0,         // partial O, kvp=0: [bh][qt][128][64]
    unsigned short* __restrict__ P1,         // partial O, kvp=1
    float* __restrict__ MLp)                 // [kvp][bh][qt][2][128]
{
    const int bid = blockIdx.x;
    const int bh = bid & 15, qt = (bid >> 4) & 31, kvp = bid >> 9;
    const int q0 = qt * 128;
    const int tid = threadIdx.x, w = tid >> 6, l = tid & 63;
    const int lq = l & 31, hi = l >> 5;
    const int kvbase = kvp * 2048;

    __shared__ __align__(16) char lds[16384];   // epilogue transpose only

    const unsigned short* Qb = Qh + (size_t)bh * SEQ * DK;
    const unsigned short* Kb = Kh + (size_t)bh * SEQ * DK;
    const unsigned short* Vb = Vtp + (size_t)bh * DK * SEQ;

    // Q fragments (B-operand): lane holds Q[q0+w*32+lq][ks*16 + hi*8 .. +7]
    bh8 qf[4];
    #pragma unroll
    for (int ks = 0; ks < 4; ++ks)
        qf[ks] = *(const bh8*)(Qb + (size_t)(q0 + w * 32 + lq) * DK + ks * 16 + hi * 8);

    // per-lane fragment bases (proven formulas = R8's pre-swizzle srcoff):
    //   K frag (rh,ks): Kb[(kv0 + rh*32 + lq)*DK + ks*16 + hi*8]
    //   V frag (rh,ks): Vb[(rh*32 + lq)*SEQ + kv0 + ks*16 + hi*8]
    const unsigned short* Kl0 = Kb + (size_t)(kvbase + lq) * DK + hi * 8;
    const unsigned short* Kl1 = Kb + (size_t)(kvbase + 32 + lq) * DK + hi * 8;
    const unsigned short* Vl0 = Vb + (size_t)lq * SEQ + kvbase + hi * 8;
    const unsigned short* Vl1 = Vb + (size_t)(32 + lq) * SEQ + kvbase + hi * 8;

    f16x o0 = {}, o1 = {};
    float m_run = -3.0e38f, l_run = 0.f;

    for (int t = 0; t < 32; ++t) {          // 32 tiles of 64 = kv 2048
        const int kv0 = t * 64;

        // ---- K fragments direct from global ----
        bh8 kf0[4], kf1[4];
        #pragma unroll
        for (int ks = 0; ks < 4; ++ks) {
            kf0[ks] = *(const bh8*)(Kl0 + (size_t)kv0 * DK + ks * 16);
            kf1[ks] = *(const bh8*)(Kl1 + (size_t)kv0 * DK + ks * 16);
        }

        // ---- S^T = K x Q ----
        f16x sa0 = {}, sa1 = {};
        __builtin_amdgcn_s_setprio(1);
        #pragma unroll
        for (int ks = 0; ks < 4; ++ks) {
            sa0 = MFMA32(kf0[ks], qf[ks], sa0);
            sa1 = MFMA32(kf1[ks], qf[ks], sa1);
        }
        __builtin_amdgcn_s_setprio(0);

        // ---- V fragments direct from global (issued under softmax) ----
        bh8 vf0[4], vf1[4];
        #pragma unroll
        for (int ks = 0; ks < 4; ++ks) {
            vf0[ks] = *(const bh8*)(Vl0 + kv0 + ks * 16);
            vf1[ks] = *(const bh8*)(Vl1 + kv0 + ks * 16);
        }

        // ---- R8-proven online softmax ----
        float a_ = fmaxf(sa0[0], sa0[1]);
        float b_ = fmaxf(sa1[0], sa1[1]);
        #pragma unroll
        for (int r = 2; r < 16; r += 2) {
            a_ = max3f(a_, sa0[r], sa0[r + 1]);
            b_ = max3f(b_, sa1[r], sa1[r + 1]);
        }
        const float mx = wave_max_pair(fmaxf(a_, b_));
        const bool skip = __all(mx <= m_run + 8.0f);
        float mnew = m_run, corr = 1.0f;
        if (!skip) {
            mnew = fmaxf(m_run, mx);
            corr = __builtin_amdgcn_exp2f(m_run - mnew);
        }
        uf U0, U1; U0.v = sa0; U1.v = sa1;
        f2 nm2; nm2[0] = -mnew; nm2[1] = -mnew;
        f2 p2[16];
        #pragma unroll
        for (int i = 0; i < 8; ++i) {
            f2 t0 = pk_add(U0.h[i], nm2);
            f2 t1 = pk_add(U1.h[i], nm2);
            f2 e0, e1;
            e0[0] = __builtin_amdgcn_exp2f(t0[0]);
            e0[1] = __builtin_amdgcn_exp2f(t0[1]);
            e1[0] = __builtin_amdgcn_exp2f(t1[0]);
            e1[1] = __builtin_amdgcn_exp2f(t1[1]);
            p2[i] = e0; p2[8 + i] = e1;
        }
        f2 s0 = pk_add(p2[0], p2[1]),   s1 = pk_add(p2[2], p2[3]);
        f2 s2 = pk_add(p2[4], p2[5]),   s3 = pk_add(p2[6], p2[7]);
        f2 s4 = pk_add(p2[8], p2[9]),   s5 = pk_add(p2[10], p2[11]);
        f2 s6 = pk_add(p2[12], p2[13]), s7 = pk_add(p2[14], p2[15]);
        s0 = pk_add(s0, s1); s2 = pk_add(s2, s3);
        s4 = pk_add(s4, s5); s6 = pk_add(s6, s7);
        s0 = pk_add(s0, s2); s4 = pk_add(s4, s6);
        s0 = pk_add(s0, s4);
        const float psum = wave_sum_pair(s0[0] + s0[1]);
        if (!skip) {
            m_run = mnew;
            l_run = l_run * corr + psum;
            f2 c2; c2[0] = corr; c2[1] = corr;
            uf O0, O1; O0.v = o0; O1.v = o1;
            #pragma unroll
            for (int i = 0; i < 8; ++i) {
                O0.h[i] = pk_mul(O0.h[i], c2);
                O1.h[i] = pk_mul(O1.h[i], c2);
            }
            o0 = O0.v; o1 = O1.v;
        } else {
            l_run += psum;
        }

        // ---- P^T -> B-fragments (cvt_pk + permlane32_swap) ----
        bh8 pf[4];
        #pragma unroll
        for (int cb = 0; cb < 2; ++cb) {
            unsigned k0 = cvtpk(p2[8 * cb + 0][0], p2[8 * cb + 0][1]);
            unsigned k1 = cvtpk(p2[8 * cb + 1][0], p2[8 * cb + 1][1]);
            unsigned k2 = cvtpk(p2[8 * cb + 2][0], p2[8 * cb + 2][1]);
            unsigned k3 = cvtpk(p2[8 * cb + 3][0], p2[8 * cb + 3][1]);
            unsigned k4 = cvtpk(p2[8 * cb + 4][0], p2[8 * cb + 4][1]);
            unsigned k5 = cvtpk(p2[8 * cb + 5][0], p2[8 * cb + 5][1]);
            unsigned k6 = cvtpk(p2[8 * cb + 6][0], p2[8 * cb + 6][1]);
            unsigned k7 = cvtpk(p2[8 * cb + 7][0], p2[8 * cb + 7][1]);
            plswap(k0, k2); plswap(k1, k3); plswap(k4, k6); plswap(k5, k7);
            union { unsigned u[4]; bh8 v; } f0, f1;
            f0.u[0] = k0; f0.u[1] = k1; f0.u[2] = k2; f0.u[3] = k3;
            f1.u[0] = k4; f1.u[1] = k5; f1.u[2] = k6; f1.u[3] = k7;
            pf[cb * 2 + 0] = f0.v;
            pf[cb * 2 + 1] = f1.v;
        }

        // ---- O^T += V^T x P^T ----
        __builtin_amdgcn_s_setprio(1);
        #pragma unroll
        for (int ks = 0; ks < 4; ++ks) {
            o0 = MFMA32(vf0[ks], pf[ks], o0);
            o1 = MFMA32(vf1[ks], pf[ks], o1);
        }
        __builtin_amdgcn_s_setprio(0);
    }

    // ---- epilogue (R12-validated): unnormalized O^T -> [q][d] partial ----
    char* Tb = lds + w * 4096;     // per-wave 32 q-rows x 128 B
    #pragma unroll
    for (int db = 0; db < 2; ++db) {
        f16x ov = db ? o1 : o0;
        #pragma unroll
        for (int j = 0; j < 8; ++j) {
            const int r = 2 * j;
            const int d = db * 32 + (r & 3) + 8 * (r >> 2) + 4 * hi;
            unsigned pk = cvtpk(ov[r], ov[r + 1]);
            *(unsigned*)(Tb + lq * 128 + ((d * 2) ^ ((lq & 7) << 4))) = pk;
        }
    }
    __syncthreads();
    unsigned short* po = kvp ? P1 : P0;
    const int row = l >> 1, half = l & 1;
    const int qloc = w * 32 + row;
    unsigned short* dst = po + (((size_t)bh * 32 + qt) * 128 + qloc) * 64 + half * 32;
    #pragma unroll
    for (int i = 0; i < 4; ++i) {
        const int byte = (half * 64 + i * 16) ^ ((row & 7) << 4);
        *(uint4*)(dst + i * 8) = *(const uint4*)(Tb + row * 128 + byte);
    }
    if (hi == 0) {
        float* mlb = MLp + (((size_t)kvp * 16 + bh) * 32 + qt) * 256;
        mlb[w * 32 + lq] = m_run;
        mlb[128 + w * 32 + lq] = l_run;
    }
}

// ---------------------------------------------------------------------------
// merge_k: Ow[q][:] = (P0*c0 + P1*c1) / l_tot  (R12-validated, verbatim).
// ---------------------------------------------------------------------------
__global__ __launch_bounds__(256) void merge_k(
    const unsigned short* __restrict__ P0,
    const unsigned short* __restrict__ P1,
    const float* __restrict__ MLp,
    unsigned short* __restrict__ Ow)
{
    const int qt = blockIdx.x, bh = blockIdx.y;
    const int tid = threadIdx.x;
    __shared__ float C0[128], C1[128];
    if (tid < 128) {
        const float* m0b = MLp + (((size_t)bh) * 32 + qt) * 256;
        const float* m1b = MLp + (((size_t)16 + bh) * 32 + qt) * 256;
        const float m0 = m0b[tid], l0 = m0b[128 + tid];
        const float m1 = m1b[tid], l1 = m1b[128 + tid];
        const float m = fmaxf(m0, m1);
        const float c0 = __builtin_amdgcn_exp2f(m0 - m);
        const float c1 = __builtin_amdgcn_exp2f(m1 - m);
        const float inv = 1.0f / (l0 * c0 + l1 * c1);
        C0[tid] = c0 * inv;
        C1[tid] = c1 * inv;
    }
    __syncthreads();
    const int q = tid >> 1, half = tid & 1;
    const float c0 = C0[q], c1 = C1[q];
    const size_t off = (((size_t)bh * 32 + qt) * 128 + q) * 64 + half * 32;
    const int b = bh >> 3, h = bh & 7;
    unsigned short* dst = Ow + ((size_t)b * SEQ + qt * 128 + q) * DMODEL + h * DK + half * 32;
    #pragma unroll
    for (int i = 0; i < 4; ++i) {
        uint4 a = *(const uint4*)(P0 + off + i * 8);
        uint4 bb = *(const uint4*)(P1 + off + i * 8);
        uint4 o;
        unsigned* ap = (unsigned*)&a;
        unsigned* bp = (unsigned*)&bb;
        unsigned* op = (unsigned*)&o;
        #pragma unroll
        for (int k = 0; k < 4; ++k) {
            const unsigned ua = ap[k], ub = bp[k];
            op[k] = cvtpk(lo2f(ua) * c0 + lo2f(ub) * c1,
                          hi2f(ua) * c0 + hi2f(ub) * c1);
        }
        *(uint4*)(dst + i * 8) = o;
    }
}

// ---------------------------------------------------------------------------
// out = Ow(bf16) @ Wo^T(bf16) -> fp32
// ---------------------------------------------------------------------------
__global__ __launch_bounds__(256) void out_gemm_mfma(
    const unsigned short* __restrict__ Ob,
    const unsigned short* __restrict__ Wob,
    float* __restrict__ out)
{
    const int m0 = blockIdx.x * 128, n0 = blockIdx.y * 128;
    const int tid = threadIdx.x, w = tid >> 6, l = tid & 63;
    const int wr = w >> 1, wc = w & 1;

    __shared__ __align__(16) unsigned short As[128 * 32];
    __shared__ __align__(16) unsigned short Bs[128 * 32];

    f4 acc[4][4] = {};
    const int lrow = l >> 2, lslot = l & 3;

    for (int k0 = 0; k0 < DMODEL; k0 += 32) {
        __syncthreads();
        #pragma unroll
        for (int j = 0; j < 2; ++j) {
            const int row = w * 32 + j * 16 + lrow;
            const int sw = lslot ^ ((row >> 1) & 3);
            GLL16(Ob + (size_t)(m0 + row) * DMODEL + k0 + sw * 8,
                  (char*)As + (w * 32 + j * 16) * 64);
            GLL16(Wob + (size_t)(n0 + row) * DMODEL + k0 + sw * 8,
                  (char*)Bs + (w * 32 + j * 16) * 64);
        }
        __syncthreads();
        bh8 af[4], bg[4];
        #pragma unroll
        for (int mi = 0; mi < 4; ++mi) {
            const int r = wr * 64 + mi * 16 + (l & 15);
            af[mi] = *(const bh8*)((const char*)As + r * 64 +
                                   (((l >> 4) * 16) ^ (((r >> 1) & 3) << 4)));
        }
        #pragma unroll
        for (int ni = 0; ni < 4; ++ni) {
            const int r = wc * 64 + ni * 16 + (l & 15);
            bg[ni] = *(const bh8*)((const char*)Bs + r * 64 +
                                   (((l >> 4) * 16) ^ (((r >> 1) & 3) << 4)));
        }
        #pragma unroll
        for (int mi = 0; mi < 4; ++mi)
            #pragma unroll
            for (int ni = 0; ni < 4; ++ni)
                acc[mi][ni] = MFMA(af[mi], bg[ni], acc[mi][ni]);
    }

    #pragma unroll
    for (int mi = 0; mi < 4; ++mi) {
        #pragma unroll
        for (int rg = 0; rg < 4; ++rg) {
            const int m = m0 + wr * 64 + mi * 16 + (l >> 4) * 4 + rg;
            #pragma unroll
            for (int ni = 0; ni < 4; ++ni) {
                const int n = n0 + wc * 64 + ni * 16 + (l & 15);
                out[(size_t)m * DMODEL + n] = acc[mi][ni][rg];
            }
        }
    }
}

extern "C" void kernel_launch(void* const* d_in, const int* in_sizes, int n_in,
                              void* d_out, int out_size, void* d_ws, size_t ws_size,
                              hipStream_t stream)
{
    const float* x  = (const float*)d_in[0];
    const float* Wq = (const float*)d_in[1];
    const float* Wk = (const float*)d_in[2];
    const float* Wv = (const float*)d_in[3];
    const float* Wo = (const float*)d_in[4];
    float* out = (float*)d_out;

    unsigned short* ws = (unsigned short*)d_ws;
    unsigned short* xb  = ws;                         // 4194304 (reused: P0)
    unsigned short* Wb  = xb + 4194304;               // 4 x 262144 (wq/wk reused: ML)
    unsigned short* QKV = Wb + 4 * 262144;            // 3 x 4194304
    unsigned short* Vt  = QKV + 3 * 4194304;          // 4194304
    unsigned short* Ow  = Vt + 4194304;               // 4194304
    unsigned short* Qh = QKV;
    unsigned short* Kh = QKV + 4194304;
    unsigned short* Vh = QKV + 2 * 4194304;           // dead after vtrans: P1

    unsigned short* P0 = xb;          // 16*32*128*64 = 4194304 shorts (exact fit)
    unsigned short* P1 = Vh;          // same size, dead region during flash
    float* MLp = (float*)Wb;          // 2*16*32*256 = 262144 floats (wq+wk, dead)

    convert_k<<<5120, 256, 0, stream>>>(x, Wq, Wk, Wv, Wo, ws);
    qkv_gemm_mfma<<<dim3(MTOT / 128, DMODEL / 128, 3), 256, 0, stream>>>(xb, Wb, QKV);
    vtrans<<<dim3(SEQ / 64, NBH), 256, 0, stream>>>(Vh, Vt);
    flash_direct<<<1024, 256, 0, stream>>>(Qh, Kh, Vt, P0, P1, MLp);
    merge_k<<<dim3(32, 16), 256, 0, stream>>>(P0, P1, MLp, Ow);
    out_gemm_mfma<<<dim3(MTOT / 128, DMODEL / 128), 256, 0, stream>>>(
        Ow, Wb + 3 * 262144, out);
}

// Round 16
// 145.963 us; speedup vs baseline: 1.9653x; 1.9653x over previous
//
#include <hip/hip_runtime.h>
#include <hip/hip_bf16.h>

#define SEQ 4096
#define DMODEL 512
#define HEADS 8
#define DK 64
#define BATCH 2
#define MTOT (BATCH * SEQ)     // 8192
#define NBH (BATCH * HEADS)    // 16

typedef __attribute__((ext_vector_type(8))) short bh8;    // 8 bf16 (4 VGPR)
typedef __attribute__((ext_vector_type(4))) float f4;
typedef __attribute__((ext_vector_type(16))) float f16x;
typedef __attribute__((ext_vector_type(2))) float f2;

union uf { f16x v; f2 h[8]; };

#define MFMA(a, b, c)   __builtin_amdgcn_mfma_f32_16x16x32_bf16(a, b, c, 0, 0, 0)
#define MFMA32(a, b, c) __builtin_amdgcn_mfma_f32_32x32x16_bf16(a, b, c, 0, 0, 0)
#define GLL16(g, l) __builtin_amdgcn_global_load_lds( \
    (const __attribute__((address_space(1))) void*)(g), \
    (__attribute__((address_space(3))) void*)(l), 16, 0, 0)

__device__ __forceinline__ unsigned short f2b(float f) {
    union { float f; unsigned u; } v; v.f = f;
    unsigned r = v.u + 0x7fff + ((v.u >> 16) & 1);   // RNE, finite inputs
    return (unsigned short)(r >> 16);
}
__device__ __forceinline__ float lo2f(unsigned u) {
    union { unsigned u; float f; } v; v.u = u << 16; return v.f;
}
__device__ __forceinline__ float hi2f(unsigned u) {
    union { unsigned u; float f; } v; v.u = u & 0xffff0000u; return v.f;
}

__device__ __forceinline__ unsigned cvtpk(float lo, float hi) {
    unsigned r;
    asm("v_cvt_pk_bf16_f32 %0, %1, %2" : "=v"(r) : "v"(lo), "v"(hi));
    return r;
}
__device__ __forceinline__ void plswap(unsigned& a, unsigned& b) {
    asm("v_permlane32_swap_b32 %0, %1" : "+v"(a), "+v"(b));
}
__device__ __forceinline__ float wave_max_pair(float x) {
    float b = x; asm("" : "+v"(b));
    float a = x;
    asm("v_permlane32_swap_b32 %0, %1" : "+v"(a), "+v"(b));
    return fmaxf(a, b);
}
__device__ __forceinline__ float wave_sum_pair(float x) {
    float b = x; asm("" : "+v"(b));
    float a = x;
    asm("v_permlane32_swap_b32 %0, %1" : "+v"(a), "+v"(b));
    return a + b;
}
__device__ __forceinline__ f2 pk_add(f2 a, f2 b) {
    f2 d; asm("v_pk_add_f32 %0, %1, %2" : "=v"(d) : "v"(a), "v"(b)); return d;
}
__device__ __forceinline__ f2 pk_mul(f2 a, f2 b) {
    f2 d; asm("v_pk_mul_f32 %0, %1, %2" : "=v"(d) : "v"(a), "v"(b)); return d;
}
__device__ __forceinline__ float max3f(float a, float b, float c) {
    float d; asm("v_max3_f32 %0, %1, %2, %3" : "=v"(d) : "v"(a), "v"(b), "v"(c));
    return d;
}

// ---------------------------------------------------------------------------
// fp32 -> bf16 conversion: [x | wq | wk | wv | wo]
// ---------------------------------------------------------------------------
__global__ __launch_bounds__(256) void convert_k(
    const float* __restrict__ x, const float* __restrict__ wq,
    const float* __restrict__ wk, const float* __restrict__ wv,
    const float* __restrict__ wo, unsigned short* __restrict__ dst)
{
    const size_t i = ((size_t)blockIdx.x * 256 + threadIdx.x) * 4;
    const float* s; size_t o;
    if (i < 4194304u)                 { s = x;  o = i; }
    else if (i < 4194304u + 262144u)  { s = wq; o = i - 4194304u; }
    else if (i < 4194304u + 524288u)  { s = wk; o = i - (4194304u + 262144u); }
    else if (i < 4194304u + 786432u)  { s = wv; o = i - (4194304u + 524288u); }
    else                              { s = wo; o = i - (4194304u + 786432u); }
    float4 v = *(const float4*)(s + o);
    ushort4 u; u.x = f2b(v.x); u.y = f2b(v.y); u.z = f2b(v.z); u.w = f2b(v.w);
    *(ushort4*)(dst + i) = u;
}

// ---------------------------------------------------------------------------
// QKV projection (MFMA, 128x128 tile). Q pre-scaled by 0.125*log2(e) so the
// flash kernel works in exp2 domain (softmax is base-invariant).
// ---------------------------------------------------------------------------
__global__ __launch_bounds__(256) void qkv_gemm_mfma(
    const unsigned short* __restrict__ xb,
    const unsigned short* __restrict__ Wb,
    unsigned short* __restrict__ QKV)
{
    const int z = blockIdx.z;
    const unsigned short* A = xb;
    const unsigned short* B = Wb + (size_t)z * (DMODEL * DMODEL);
    const int m0 = blockIdx.x * 128, n0 = blockIdx.y * 128;
    const int tid = threadIdx.x, w = tid >> 6, l = tid & 63;
    const int wr = w >> 1, wc = w & 1;

    __shared__ __align__(16) unsigned short As[128 * 32];
    __shared__ __align__(16) unsigned short Bs[128 * 32];

    f4 acc[4][4] = {};
    const int lrow = l >> 2, lslot = l & 3;

    for (int k0 = 0; k0 < DMODEL; k0 += 32) {
        __syncthreads();
        #pragma unroll
        for (int j = 0; j < 2; ++j) {
            const int row = w * 32 + j * 16 + lrow;
            const int sw = lslot ^ ((row >> 1) & 3);
            GLL16(A + (size_t)(m0 + row) * DMODEL + k0 + sw * 8,
                  (char*)As + (w * 32 + j * 16) * 64);
            GLL16(B + (size_t)(n0 + row) * DMODEL + k0 + sw * 8,
                  (char*)Bs + (w * 32 + j * 16) * 64);
        }
        __syncthreads();
        bh8 af[4], bg[4];
        #pragma unroll
        for (int mi = 0; mi < 4; ++mi) {
            const int r = wr * 64 + mi * 16 + (l & 15);
            af[mi] = *(const bh8*)((const char*)As + r * 64 +
                                   (((l >> 4) * 16) ^ (((r >> 1) & 3) << 4)));
        }
        #pragma unroll
        for (int ni = 0; ni < 4; ++ni) {
            const int r = wc * 64 + ni * 16 + (l & 15);
            bg[ni] = *(const bh8*)((const char*)Bs + r * 64 +
                                   (((l >> 4) * 16) ^ (((r >> 1) & 3) << 4)));
        }
        #pragma unroll
        for (int mi = 0; mi < 4; ++mi)
            #pragma unroll
            for (int ni = 0; ni < 4; ++ni)
                acc[mi][ni] = MFMA(af[mi], bg[ni], acc[mi][ni]);
    }

    unsigned short* Out = QKV + (size_t)z * ((size_t)NBH * SEQ * DK);
    const float sc = (z == 0) ? 0.18033688011112042f : 1.0f;  // 0.125*log2e
    #pragma unroll
    for (int mi = 0; mi < 4; ++mi) {
        #pragma unroll
        for (int rg = 0; rg < 4; ++rg) {
            const int m = m0 + wr * 64 + mi * 16 + (l >> 4) * 4 + rg;
            const int b = m >> 12, t = m & (SEQ - 1);
            #pragma unroll
            for (int ni = 0; ni < 4; ++ni) {
                const int n = n0 + wc * 64 + ni * 16 + (l & 15);
                const int h = n >> 6, d = n & 63;
                Out[(((size_t)(b * HEADS + h)) * SEQ + t) * DK + d] =
                    f2b(acc[mi][ni][rg] * sc);
            }
        }
    }
}

// ---------------------------------------------------------------------------
// V [bh][t][d] -> Vt [bh][d][t]
// ---------------------------------------------------------------------------
__global__ __launch_bounds__(256) void vtrans(
    const unsigned short* __restrict__ Vh, unsigned short* __restrict__ Vt)
{
    const int bh = blockIdx.y, t0 = blockIdx.x * 64;
    __shared__ unsigned short L[64][72];
    const unsigned short* src = Vh + ((size_t)bh * SEQ + t0) * DK;
    const int r = threadIdx.x >> 3, c8 = (threadIdx.x & 7) * 8;
    #pragma unroll
    for (int it = 0; it < 2; ++it) {
        const int row = r + it * 32;
        ushort4 a = *(const ushort4*)(src + (size_t)row * DK + c8);
        ushort4 b = *(const ushort4*)(src + (size_t)row * DK + c8 + 4);
        L[row][c8 + 0] = a.x; L[row][c8 + 1] = a.y; L[row][c8 + 2] = a.z; L[row][c8 + 3] = a.w;
        L[row][c8 + 4] = b.x; L[row][c8 + 5] = b.y; L[row][c8 + 6] = b.z; L[row][c8 + 7] = b.w;
    }
    __syncthreads();
    unsigned short* dst = Vt + (size_t)bh * DK * SEQ + t0;
    #pragma unroll
    for (int it = 0; it < 2; ++it) {
        const int d = r + it * 32;
        ushort4 a, b;
        a.x = L[c8 + 0][d]; a.y = L[c8 + 1][d]; a.z = L[c8 + 2][d]; a.w = L[c8 + 3][d];
        b.x = L[c8 + 4][d]; b.y = L[c8 + 5][d]; b.z = L[c8 + 6][d]; b.w = L[c8 + 7][d];
        *(ushort4*)(dst + (size_t)d * SEQ + c8) = a;
        *(ushort4*)(dst + (size_t)d * SEQ + c8 + 4) = b;
    }
}

// ---------------------------------------------------------------------------
// Flash attention = R14's PROVEN 8-wave kernel + R12's VALIDATED kvp-split.
// Grid 512 = 16bh x 16qt x 2kvp; 512 thr; q-tile 256 (32 q-rows/wave, R14
// per-wave code byte-identical); each block covers kv-2048 with in-wave A/B
// halves over [kvbase,+1024)/[+1024,+2048), 16 iterations of kv-tile 64.
// 2 blocks/CU (128 KB LDS, 16 waves/CU): restores R8's cross-block barrier
// overlap at 2x R14's wave count. Writes unnormalized partial O + (m,l);
// merge_k combines (R12-validated formula).
// ---------------------------------------------------------------------------
__global__ __launch_bounds__(512, 2) void flash_mfma(
    const unsigned short* __restrict__ Qh,   // [NBH][SEQ][DK], pre-scaled
    const unsigned short* __restrict__ Kh,   // [NBH][SEQ][DK]
    const unsigned short* __restrict__ Vtp,  // [NBH][DK][SEQ]
    unsigned short* __restrict__ P0,         // partial O, kvp=0: [bh][qt16][256][64]
    unsigned short* __restrict__ P1,         // partial O, kvp=1
    float* __restrict__ MLp)                 // [kvp][bh][qt16][2][256]
{
    const int bid = blockIdx.x;
    const int bh = bid & 15, qt = (bid >> 4) & 15, kvp = bid >> 8;
    const int q0 = qt * 256;
    const int tid = threadIdx.x, w = tid >> 6, l = tid & 63;
    const int lq = l & 31, hi = l >> 5;
    const int kvbase = kvp * 2048;

    // [2 bufs][2 halves][ K frags 8KB | V frags 8KB ] = 64 KB
    __shared__ __align__(16) char lds[65536];

    const unsigned short* Qb = Qh + (size_t)bh * SEQ * DK;
    const unsigned short* Kb = Kh + (size_t)bh * SEQ * DK;
    const unsigned short* Vb = Vtp + (size_t)bh * DK * SEQ;

    // Q fragments (B-operand): lane holds Q[q0+w*32+lq][ks*16 + hi*8 .. +7]
    bh8 qf[4];
    #pragma unroll
    for (int ks = 0; ks < 4; ++ks)
        qf[ks] = *(const bh8*)(Qb + (size_t)(q0 + w * 32 + lq) * DK + ks * 16 + hi * 8);

    // staging source offsets (elems): wave w stages frag f = w per half
    const int koff = ((w >> 2) * 32 + lq) * DK + (w & 3) * 16 + hi * 8;
    const int voff = ((w >> 2) * 32 + lq) * SEQ + (w & 3) * 16 + hi * 8;

    f16x oA0 = {}, oA1 = {}, oB0 = {}, oB1 = {};
    float mA = -3.0e38f, lA = 0.f, mB = -3.0e38f, lB = 0.f;

#define STAGE(buf_, half_, kv0_) do {                                         \
    GLL16(Kb + (size_t)(kvbase + (half_) * 1024 + (kv0_)) * DK + koff,        \
          lds + (buf_) * 32768 + (half_) * 16384 + w * 1024);                 \
    GLL16(Vb + (size_t)(kvbase + (half_) * 1024 + (kv0_)) + voff,             \
          lds + (buf_) * 32768 + (half_) * 16384 + 8192 + w * 1024);          \
} while (0)

// QK^T of one 64-tile from fragment-major LDS base kb_
#define QKT(kb_, sa0_, sa1_) do {                                             \
    __builtin_amdgcn_s_setprio(1);                                            \
    _Pragma("unroll")                                                         \
    for (int ks_ = 0; ks_ < 4; ++ks_) {                                       \
        bh8 k0_ = *(const bh8*)((kb_) + ks_ * 1024);                          \
        bh8 k1_ = *(const bh8*)((kb_) + (4 + ks_) * 1024);                    \
        sa0_ = MFMA32(k0_, qf[ks_], sa0_);                                    \
        sa1_ = MFMA32(k1_, qf[ks_], sa1_);                                    \
    }                                                                         \
    __builtin_amdgcn_s_setprio(0);                                            \
} while (0)

// R4-proven online softmax + P-pack + PV for one tile
#define SMPV(kb_, sa0_, sa1_, m_run_, l_run_, o0_, o1_) do {                  \
    float a_ = fmaxf(sa0_[0], sa0_[1]);                                       \
    float b_ = fmaxf(sa1_[0], sa1_[1]);                                       \
    _Pragma("unroll")                                                         \
    for (int r_ = 2; r_ < 16; r_ += 2) {                                      \
        a_ = max3f(a_, sa0_[r_], sa0_[r_ + 1]);                               \
        b_ = max3f(b_, sa1_[r_], sa1_[r_ + 1]);                               \
    }                                                                         \
    const float mx_ = wave_max_pair(fmaxf(a_, b_));                           \
    const bool skip_ = __all(mx_ <= m_run_ + 8.0f);                           \
    float mnew_ = m_run_, corr_ = 1.0f;                                       \
    if (!skip_) {                                                             \
        mnew_ = fmaxf(m_run_, mx_);                                           \
        corr_ = __builtin_amdgcn_exp2f(m_run_ - mnew_);                       \
    }                                                                         \
    uf U0_, U1_; U0_.v = sa0_; U1_.v = sa1_;                                  \
    f2 nm2_; nm2_[0] = -mnew_; nm2_[1] = -mnew_;                              \
    f2 p2_[16];                                                               \
    _Pragma("unroll")                                                         \
    for (int i_ = 0; i_ < 8; ++i_) {                                          \
        f2 t0_ = pk_add(U0_.h[i_], nm2_);                                     \
        f2 t1_ = pk_add(U1_.h[i_], nm2_);                                     \
        f2 e0_, e1_;                                                          \
        e0_[0] = __builtin_amdgcn_exp2f(t0_[0]);                              \
        e0_[1] = __builtin_amdgcn_exp2f(t0_[1]);                              \
        e1_[0] = __builtin_amdgcn_exp2f(t1_[0]);                              \
        e1_[1] = __builtin_amdgcn_exp2f(t1_[1]);                              \
        p2_[i_] = e0_; p2_[8 + i_] = e1_;                                     \
    }                                                                         \
    f2 s0_ = pk_add(p2_[0], p2_[1]),   s1_ = pk_add(p2_[2], p2_[3]);          \
    f2 s2_ = pk_add(p2_[4], p2_[5]),   s3_ = pk_add(p2_[6], p2_[7]);          \
    f2 s4_ = pk_add(p2_[8], p2_[9]),   s5_ = pk_add(p2_[10], p2_[11]);        \
    f2 s6_ = pk_add(p2_[12], p2_[13]), s7_ = pk_add(p2_[14], p2_[15]);        \
    s0_ = pk_add(s0_, s1_); s2_ = pk_add(s2_, s3_);                           \
    s4_ = pk_add(s4_, s5_); s6_ = pk_add(s6_, s7_);                           \
    s0_ = pk_add(s0_, s2_); s4_ = pk_add(s4_, s6_);                           \
    s0_ = pk_add(s0_, s4_);                                                   \
    const float psum_ = wave_sum_pair(s0_[0] + s0_[1]);                       \
    if (!skip_) {                                                             \
        m_run_ = mnew_;                                                       \
        l_run_ = l_run_ * corr_ + psum_;                                      \
        f2 c2_; c2_[0] = corr_; c2_[1] = corr_;                               \
        uf O0_, O1_; O0_.v = o0_; O1_.v = o1_;                                \
        _Pragma("unroll")                                                     \
        for (int i_ = 0; i_ < 8; ++i_) {                                      \
            O0_.h[i_] = pk_mul(O0_.h[i_], c2_);                               \
            O1_.h[i_] = pk_mul(O1_.h[i_], c2_);                               \
        }                                                                     \
        o0_ = O0_.v; o1_ = O1_.v;                                             \
    } else {                                                                  \
        l_run_ += psum_;                                                      \
    }                                                                         \
    bh8 pf_[4];                                                               \
    _Pragma("unroll")                                                         \
    for (int cb_ = 0; cb_ < 2; ++cb_) {                                       \
        unsigned k0_ = cvtpk(p2_[8 * cb_ + 0][0], p2_[8 * cb_ + 0][1]);       \
        unsigned k1_ = cvtpk(p2_[8 * cb_ + 1][0], p2_[8 * cb_ + 1][1]);       \
        unsigned k2_ = cvtpk(p2_[8 * cb_ + 2][0], p2_[8 * cb_ + 2][1]);       \
        unsigned k3_ = cvtpk(p2_[8 * cb_ + 3][0], p2_[8 * cb_ + 3][1]);       \
        unsigned k4_ = cvtpk(p2_[8 * cb_ + 4][0], p2_[8 * cb_ + 4][1]);       \
        unsigned k5_ = cvtpk(p2_[8 * cb_ + 5][0], p2_[8 * cb_ + 5][1]);       \
        unsigned k6_ = cvtpk(p2_[8 * cb_ + 6][0], p2_[8 * cb_ + 6][1]);       \
        unsigned k7_ = cvtpk(p2_[8 * cb_ + 7][0], p2_[8 * cb_ + 7][1]);       \
        plswap(k0_, k2_); plswap(k1_, k3_); plswap(k4_, k6_); plswap(k5_, k7_);\
        union { unsigned u[4]; bh8 v; } f0_, f1_;                             \
        f0_.u[0] = k0_; f0_.u[1] = k1_; f0_.u[2] = k2_; f0_.u[3] = k3_;       \
        f1_.u[0] = k4_; f1_.u[1] = k5_; f1_.u[2] = k6_; f1_.u[3] = k7_;       \
        pf_[cb_ * 2 + 0] = f0_.v;                                             \
        pf_[cb_ * 2 + 1] = f1_.v;                                             \
    }                                                                         \
    const char* vb_ = (kb_) + 8192;                                           \
    __builtin_amdgcn_s_setprio(1);                                            \
    _Pragma("unroll")                                                         \
    for (int ks_ = 0; ks_ < 4; ++ks_) {                                       \
        bh8 v0_ = *(const bh8*)(vb_ + ks_ * 1024);                            \
        bh8 v1_ = *(const bh8*)(vb_ + (4 + ks_) * 1024);                      \
        o0_ = MFMA32(v0_, pf_[ks_], o0_);                                     \
        o1_ = MFMA32(v1_, pf_[ks_], o1_);                                     \
    }                                                                         \
    __builtin_amdgcn_s_setprio(0);                                            \
} while (0)

    STAGE(0, 0, 0);
    STAGE(0, 1, 0);
    __syncthreads();
    int cur = 0;
    const char* myfrag = lds + l * 16;

    for (int t = 0; t < 16; ++t) {          // 16 tiles of 64 per half = 1024
        if (t < 15) {
            STAGE(cur ^ 1, 0, (t + 1) * 64);
            STAGE(cur ^ 1, 1, (t + 1) * 64);
        }

        const char* kbA = myfrag + cur * 32768;            // half A K frags
        const char* kbB = kbA + 16384;                     // half B K frags

        f16x sA0 = {}, sA1 = {}, sB0 = {}, sB1 = {};
        QKT(kbA, sA0, sA1);
        QKT(kbB, sB0, sB1);
        SMPV(kbA, sA0, sA1, mA, lA, oA0, oA1);
        SMPV(kbB, sB0, sB1, mB, lB, oB0, oB1);

        __syncthreads();
        cur ^= 1;
    }
#undef STAGE
#undef QKT
#undef SMPV

    // ---- in-register, in-lane merge of the two kv-half states ----
    const float mt = fmaxf(mA, mB);
    const float cA = __builtin_amdgcn_exp2f(mA - mt);
    const float cB = __builtin_amdgcn_exp2f(mB - mt);
    f16x o0, o1;
    #pragma unroll
    for (int r = 0; r < 16; ++r) {
        o0[r] = oA0[r] * cA + oB0[r] * cB;
        o1[r] = oA1[r] * cA + oB1[r] * cB;
    }
    const float l_tot = lA * cA + lB * cB;

    // ---- epilogue: UNNORMALIZED O^T -> [q][d] partial via swizzled LDS ----
    char* Tb = lds + w * 4096;     // per-wave 32 q-rows x 128 B (8 waves=32KB)
    #pragma unroll
    for (int db = 0; db < 2; ++db) {
        f16x ov = db ? o1 : o0;
        #pragma unroll
        for (int j = 0; j < 8; ++j) {
            const int r = 2 * j;
            const int d = db * 32 + (r & 3) + 8 * (r >> 2) + 4 * hi;
            unsigned pk = cvtpk(ov[r], ov[r + 1]);
            *(unsigned*)(Tb + lq * 128 + ((d * 2) ^ ((lq & 7) << 4))) = pk;
        }
    }
    __syncthreads();
    unsigned short* po = kvp ? P1 : P0;
    const int row = l >> 1, half = l & 1;
    const int qloc = w * 32 + row;
    unsigned short* dst = po + (((size_t)bh * 16 + qt) * 256 + qloc) * 64 + half * 32;
    #pragma unroll
    for (int i = 0; i < 4; ++i) {
        const int byte = (half * 64 + i * 16) ^ ((row & 7) << 4);
        *(uint4*)(dst + i * 8) = *(const uint4*)(Tb + row * 128 + byte);
    }
    if (hi == 0) {
        float* mlb = MLp + (((size_t)kvp * 16 + bh) * 16 + qt) * 512;
        mlb[w * 32 + lq] = mt;
        mlb[256 + w * 32 + lq] = l_tot;
    }
}

// ---------------------------------------------------------------------------
// merge_k: Ow[q][:] = (P0*c0 + P1*c1) / l_tot  (R12-validated formula,
// re-indexed for [bh][qt16][256][64]). grid (16 qt, 16 bh), 512 threads.
// ---------------------------------------------------------------------------
__global__ __launch_bounds__(512) void merge_k(
    const unsigned short* __restrict__ P0,
    const unsigned short* __restrict__ P1,
    const float* __restrict__ MLp,
    unsigned short* __restrict__ Ow)
{
    const int qt = blockIdx.x, bh = blockIdx.y;
    const int tid = threadIdx.x;
    __shared__ float C0[256], C1[256];
    if (tid < 256) {
        const float* m0b = MLp + (((size_t)bh) * 16 + qt) * 512;
        const float* m1b = MLp + (((size_t)16 + bh) * 16 + qt) * 512;
        const float m0 = m0b[tid], l0 = m0b[256 + tid];
        const float m1 = m1b[tid], l1 = m1b[256 + tid];
        const float m = fmaxf(m0, m1);
        const float c0 = __builtin_amdgcn_exp2f(m0 - m);
        const float c1 = __builtin_amdgcn_exp2f(m1 - m);
        const float inv = 1.0f / (l0 * c0 + l1 * c1);
        C0[tid] = c0 * inv;
        C1[tid] = c1 * inv;
    }
    __syncthreads();
    const int q = tid >> 1, half = tid & 1;
    const float c0 = C0[q], c1 = C1[q];
    const size_t off = (((size_t)bh * 16 + qt) * 256 + q) * 64 + half * 32;
    const int b = bh >> 3, h = bh & 7;
    unsigned short* dst = Ow + ((size_t)b * SEQ + qt * 256 + q) * DMODEL + h * DK + half * 32;
    #pragma unroll
    for (int i = 0; i < 4; ++i) {
        uint4 a = *(const uint4*)(P0 + off + i * 8);
        uint4 bb = *(const uint4*)(P1 + off + i * 8);
        uint4 o;
        unsigned* ap = (unsigned*)&a;
        unsigned* bp = (unsigned*)&bb;
        unsigned* op = (unsigned*)&o;
        #pragma unroll
        for (int k = 0; k < 4; ++k) {
            const unsigned ua = ap[k], ub = bp[k];
            op[k] = cvtpk(lo2f(ua) * c0 + lo2f(ub) * c1,
                          hi2f(ua) * c0 + hi2f(ub) * c1);
        }
        *(uint4*)(dst + i * 8) = o;
    }
}

// ---------------------------------------------------------------------------
// out = Ow(bf16) @ Wo^T(bf16) -> fp32
// ---------------------------------------------------------------------------
__global__ __launch_bounds__(256) void out_gemm_mfma(
    const unsigned short* __restrict__ Ob,
    const unsigned short* __restrict__ Wob,
    float* __restrict__ out)
{
    const int m0 = blockIdx.x * 128, n0 = blockIdx.y * 128;
    const int tid = threadIdx.x, w = tid >> 6, l = tid & 63;
    const int wr = w >> 1, wc = w & 1;

    __shared__ __align__(16) unsigned short As[128 * 32];
    __shared__ __align__(16) unsigned short Bs[128 * 32];

    f4 acc[4][4] = {};
    const int lrow = l >> 2, lslot = l & 3;

    for (int k0 = 0; k0 < DMODEL; k0 += 32) {
        __syncthreads();
        #pragma unroll
        for (int j = 0; j < 2; ++j) {
            const int row = w * 32 + j * 16 + lrow;
            const int sw = lslot ^ ((row >> 1) & 3);
            GLL16(Ob + (size_t)(m0 + row) * DMODEL + k0 + sw * 8,
                  (char*)As + (w * 32 + j * 16) * 64);
            GLL16(Wob + (size_t)(n0 + row) * DMODEL + k0 + sw * 8,
                  (char*)Bs + (w * 32 + j * 16) * 64);
        }
        __syncthreads();
        bh8 af[4], bg[4];
        #pragma unroll
        for (int mi = 0; mi < 4; ++mi) {
            const int r = wr * 64 + mi * 16 + (l & 15);
            af[mi] = *(const bh8*)((const char*)As + r * 64 +
                                   (((l >> 4) * 16) ^ (((r >> 1) & 3) << 4)));
        }
        #pragma unroll
        for (int ni = 0; ni < 4; ++ni) {
            const int r = wc * 64 + ni * 16 + (l & 15);
            bg[ni] = *(const bh8*)((const char*)Bs + r * 64 +
                                   (((l >> 4) * 16) ^ (((r >> 1) & 3) << 4)));
        }
        #pragma unroll
        for (int mi = 0; mi < 4; ++mi)
            #pragma unroll
            for (int ni = 0; ni < 4; ++ni)
                acc[mi][ni] = MFMA(af[mi], bg[ni], acc[mi][ni]);
    }

    #pragma unroll
    for (int mi = 0; mi < 4; ++mi) {
        #pragma unroll
        for (int rg = 0; rg < 4; ++rg) {
            const int m = m0 + wr * 64 + mi * 16 + (l >> 4) * 4 + rg;
            #pragma unroll
            for (int ni = 0; ni < 4; ++ni) {
                const int n = n0 + wc * 64 + ni * 16 + (l & 15);
                out[(size_t)m * DMODEL + n] = acc[mi][ni][rg];
            }
        }
    }
}

extern "C" void kernel_launch(void* const* d_in, const int* in_sizes, int n_in,
                              void* d_out, int out_size, void* d_ws, size_t ws_size,
                              hipStream_t stream)
{
    const float* x  = (const float*)d_in[0];
    const float* Wq = (const float*)d_in[1];
    const float* Wk = (const float*)d_in[2];
    const float* Wv = (const float*)d_in[3];
    const float* Wo = (const float*)d_in[4];
    float* out = (float*)d_out;

    unsigned short* ws = (unsigned short*)d_ws;
    unsigned short* xb  = ws;                         // 4194304 (reused: P0)
    unsigned short* Wb  = xb + 4194304;               // 4 x 262144 (wq/wk reused: ML)
    unsigned short* QKV = Wb + 4 * 262144;            // 3 x 4194304
    unsigned short* Vt  = QKV + 3 * 4194304;          // 4194304
    unsigned short* Ow  = Vt + 4194304;               // 4194304
    unsigned short* Qh = QKV;
    unsigned short* Kh = QKV + 4194304;
    unsigned short* Vh = QKV + 2 * 4194304;           // dead after vtrans: P1

    unsigned short* P0 = xb;          // 16*16*256*64 = 4194304 shorts (exact fit)
    unsigned short* P1 = Vh;          // same size, dead region during flash
    float* MLp = (float*)Wb;          // 2*16*16*512 = 262144 floats (wq+wk, dead)

    convert_k<<<5120, 256, 0, stream>>>(x, Wq, Wk, Wv, Wo, ws);
    qkv_gemm_mfma<<<dim3(MTOT / 128, DMODEL / 128, 3), 256, 0, stream>>>(xb, Wb, QKV);
    vtrans<<<dim3(SEQ / 64, NBH), 256, 0, stream>>>(Vh, Vt);
    flash_mfma<<<512, 512, 0, stream>>>(Qh, Kh, Vt, P0, P1, MLp);
    merge_k<<<dim3(16, 16), 512, 0, stream>>>(P0, P1, MLp, Ow);
    out_gemm_mfma<<<dim3(MTOT / 128, DMODEL / 128), 256, 0, stream>>>(
        Ow, Wb + 3 * 262144, out);
}

// Round 17
// 133.854 us; speedup vs baseline: 2.1431x; 1.0905x over previous
//
#include <hip/hip_runtime.h>
#include <hip/hip_bf16.h>

#define SEQ 4096
#define DMODEL 512
#define HEADS 8
#define DK 64
#define BATCH 2
#define MTOT (BATCH * SEQ)     // 8192
#define NBH (BATCH * HEADS)    // 16

typedef __attribute__((ext_vector_type(8))) short bh8;    // 8 bf16 (4 VGPR)
typedef __attribute__((ext_vector_type(4))) float f4;
typedef __attribute__((ext_vector_type(16))) float f16x;
typedef __attribute__((ext_vector_type(2))) float f2;

union uf { f16x v; f2 h[8]; };

#define MFMA(a, b, c)   __builtin_amdgcn_mfma_f32_16x16x32_bf16(a, b, c, 0, 0, 0)
#define MFMA32(a, b, c) __builtin_amdgcn_mfma_f32_32x32x16_bf16(a, b, c, 0, 0, 0)
#define GLL16(g, l) __builtin_amdgcn_global_load_lds( \
    (const __attribute__((address_space(1))) void*)(g), \
    (__attribute__((address_space(3))) void*)(l), 16, 0, 0)

__device__ __forceinline__ unsigned short f2b(float f) {
    union { float f; unsigned u; } v; v.f = f;
    unsigned r = v.u + 0x7fff + ((v.u >> 16) & 1);   // RNE, finite inputs
    return (unsigned short)(r >> 16);
}

__device__ __forceinline__ unsigned cvtpk(float lo, float hi) {
    unsigned r;
    asm("v_cvt_pk_bf16_f32 %0, %1, %2" : "=v"(r) : "v"(lo), "v"(hi));
    return r;
}
__device__ __forceinline__ void plswap(unsigned& a, unsigned& b) {
    asm("v_permlane32_swap_b32 %0, %1" : "+v"(a), "+v"(b));
}
__device__ __forceinline__ float wave_max_pair(float x) {
    float b = x; asm("" : "+v"(b));
    float a = x;
    asm("v_permlane32_swap_b32 %0, %1" : "+v"(a), "+v"(b));
    return fmaxf(a, b);
}
__device__ __forceinline__ float wave_sum_pair(float x) {
    float b = x; asm("" : "+v"(b));
    float a = x;
    asm("v_permlane32_swap_b32 %0, %1" : "+v"(a), "+v"(b));
    return a + b;
}
__device__ __forceinline__ f2 pk_add(f2 a, f2 b) {
    f2 d; asm("v_pk_add_f32 %0, %1, %2" : "=v"(d) : "v"(a), "v"(b)); return d;
}
__device__ __forceinline__ f2 pk_mul(f2 a, f2 b) {
    f2 d; asm("v_pk_mul_f32 %0, %1, %2" : "=v"(d) : "v"(a), "v"(b)); return d;
}
__device__ __forceinline__ float max3f(float a, float b, float c) {
    float d; asm("v_max3_f32 %0, %1, %2, %3" : "=v"(d) : "v"(a), "v"(b), "v"(c));
    return d;
}

// ---------------------------------------------------------------------------
// fp32 -> bf16 conversion: [x | wq | wk | wv | wo]
// ---------------------------------------------------------------------------
__global__ __launch_bounds__(256) void convert_k(
    const float* __restrict__ x, const float* __restrict__ wq,
    const float* __restrict__ wk, const float* __restrict__ wv,
    const float* __restrict__ wo, unsigned short* __restrict__ dst)
{
    const size_t i = ((size_t)blockIdx.x * 256 + threadIdx.x) * 4;
    const float* s; size_t o;
    if (i < 4194304u)                 { s = x;  o = i; }
    else if (i < 4194304u + 262144u)  { s = wq; o = i - 4194304u; }
    else if (i < 4194304u + 524288u)  { s = wk; o = i - (4194304u + 262144u); }
    else if (i < 4194304u + 786432u)  { s = wv; o = i - (4194304u + 524288u); }
    else                              { s = wo; o = i - (4194304u + 786432u); }
    float4 v = *(const float4*)(s + o);
    ushort4 u; u.x = f2b(v.x); u.y = f2b(v.y); u.z = f2b(v.z); u.w = f2b(v.w);
    *(ushort4*)(dst + i) = u;
}

// ---------------------------------------------------------------------------
// QKV projection (MFMA, 128x128 tile). Q pre-scaled by 0.125*log2(e) so the
// flash kernel works in exp2 domain (softmax is base-invariant).
// ---------------------------------------------------------------------------
__global__ __launch_bounds__(256) void qkv_gemm_mfma(
    const unsigned short* __restrict__ xb,
    const unsigned short* __restrict__ Wb,
    unsigned short* __restrict__ QKV)
{
    const int z = blockIdx.z;
    const unsigned short* A = xb;
    const unsigned short* B = Wb + (size_t)z * (DMODEL * DMODEL);
    const int m0 = blockIdx.x * 128, n0 = blockIdx.y * 128;
    const int tid = threadIdx.x, w = tid >> 6, l = tid & 63;
    const int wr = w >> 1, wc = w & 1;

    __shared__ __align__(16) unsigned short As[128 * 32];
    __shared__ __align__(16) unsigned short Bs[128 * 32];

    f4 acc[4][4] = {};
    const int lrow = l >> 2, lslot = l & 3;

    for (int k0 = 0; k0 < DMODEL; k0 += 32) {
        __syncthreads();
        #pragma unroll
        for (int j = 0; j < 2; ++j) {
            const int row = w * 32 + j * 16 + lrow;
            const int sw = lslot ^ ((row >> 1) & 3);
            GLL16(A + (size_t)(m0 + row) * DMODEL + k0 + sw * 8,
                  (char*)As + (w * 32 + j * 16) * 64);
            GLL16(B + (size_t)(n0 + row) * DMODEL + k0 + sw * 8,
                  (char*)Bs + (w * 32 + j * 16) * 64);
        }
        __syncthreads();
        bh8 af[4], bg[4];
        #pragma unroll
        for (int mi = 0; mi < 4; ++mi) {
            const int r = wr * 64 + mi * 16 + (l & 15);
            af[mi] = *(const bh8*)((const char*)As + r * 64 +
                                   (((l >> 4) * 16) ^ (((r >> 1) & 3) << 4)));
        }
        #pragma unroll
        for (int ni = 0; ni < 4; ++ni) {
            const int r = wc * 64 + ni * 16 + (l & 15);
            bg[ni] = *(const bh8*)((const char*)Bs + r * 64 +
                                   (((l >> 4) * 16) ^ (((r >> 1) & 3) << 4)));
        }
        #pragma unroll
        for (int mi = 0; mi < 4; ++mi)
            #pragma unroll
            for (int ni = 0; ni < 4; ++ni)
                acc[mi][ni] = MFMA(af[mi], bg[ni], acc[mi][ni]);
    }

    unsigned short* Out = QKV + (size_t)z * ((size_t)NBH * SEQ * DK);
    const float sc = (z == 0) ? 0.18033688011112042f : 1.0f;  // 0.125*log2e
    #pragma unroll
    for (int mi = 0; mi < 4; ++mi) {
        #pragma unroll
        for (int rg = 0; rg < 4; ++rg) {
            const int m = m0 + wr * 64 + mi * 16 + (l >> 4) * 4 + rg;
            const int b = m >> 12, t = m & (SEQ - 1);
            #pragma unroll
            for (int ni = 0; ni < 4; ++ni) {
                const int n = n0 + wc * 64 + ni * 16 + (l & 15);
                const int h = n >> 6, d = n & 63;
                Out[(((size_t)(b * HEADS + h)) * SEQ + t) * DK + d] =
                    f2b(acc[mi][ni][rg] * sc);
            }
        }
    }
}

// ---------------------------------------------------------------------------
// V [bh][t][d] -> Vt [bh][d][t]
// ---------------------------------------------------------------------------
__global__ __launch_bounds__(256) void vtrans(
    const unsigned short* __restrict__ Vh, unsigned short* __restrict__ Vt)
{
    const int bh = blockIdx.y, t0 = blockIdx.x * 64;
    __shared__ unsigned short L[64][72];
    const unsigned short* src = Vh + ((size_t)bh * SEQ + t0) * DK;
    const int r = threadIdx.x >> 3, c8 = (threadIdx.x & 7) * 8;
    #pragma unroll
    for (int it = 0; it < 2; ++it) {
        const int row = r + it * 32;
        ushort4 a = *(const ushort4*)(src + (size_t)row * DK + c8);
        ushort4 b = *(const ushort4*)(src + (size_t)row * DK + c8 + 4);
        L[row][c8 + 0] = a.x; L[row][c8 + 1] = a.y; L[row][c8 + 2] = a.z; L[row][c8 + 3] = a.w;
        L[row][c8 + 4] = b.x; L[row][c8 + 5] = b.y; L[row][c8 + 6] = b.z; L[row][c8 + 7] = b.w;
    }
    __syncthreads();
    unsigned short* dst = Vt + (size_t)bh * DK * SEQ + t0;
    #pragma unroll
    for (int it = 0; it < 2; ++it) {
        const int d = r + it * 32;
        ushort4 a, b;
        a.x = L[c8 + 0][d]; a.y = L[c8 + 1][d]; a.z = L[c8 + 2][d]; a.w = L[c8 + 3][d];
        b.x = L[c8 + 4][d]; b.y = L[c8 + 5][d]; b.z = L[c8 + 6][d]; b.w = L[c8 + 7][d];
        *(ushort4*)(dst + (size_t)d * SEQ + c8) = a;
        *(ushort4*)(dst + (size_t)d * SEQ + c8 + 4) = b;
    }
}

// ---------------------------------------------------------------------------
// Flash attention (CHAMPION, R14): 8-wave blocks (512 thr), q-tile 256,
// per-wave 32 q-rows with in-wave kv-split A/B over [0,2048)/[2048,4096);
// swapped 32x32x16 MFMA, in-register online softmax (R4-proven numerics),
// defer-max THR=8, cvt_pk+permlane P-pack; 8 waves SHARE the 64 KB LDS K/V
// tiles (1 frag staged per wave). Grid 256; bid&15=bh keeps same-bh blocks
// on one XCD -> KV L2-resident. Final A/B merge in-register, in-lane.
// ---------------------------------------------------------------------------
__global__ __launch_bounds__(512, 2) void flash_mfma(
    const unsigned short* __restrict__ Qh,   // [NBH][SEQ][DK], pre-scaled
    const unsigned short* __restrict__ Kh,   // [NBH][SEQ][DK]
    const unsigned short* __restrict__ Vtp,  // [NBH][DK][SEQ]
    unsigned short* __restrict__ Ow)         // [MTOT][DMODEL] bf16
{
    const int bid = blockIdx.x;
    const int bh = bid & 15, q0 = (bid >> 4) * 256;
    const int tid = threadIdx.x, w = tid >> 6, l = tid & 63;
    const int lq = l & 31, hi = l >> 5;

    // [2 bufs][2 halves][ K frags 8KB | V frags 8KB ] = 64 KB
    __shared__ __align__(16) char lds[65536];

    const unsigned short* Qb = Qh + (size_t)bh * SEQ * DK;
    const unsigned short* Kb = Kh + (size_t)bh * SEQ * DK;
    const unsigned short* Vb = Vtp + (size_t)bh * DK * SEQ;

    // Q fragments (B-operand): lane holds Q[q0+w*32+lq][ks*16 + hi*8 .. +7]
    bh8 qf[4];
    #pragma unroll
    for (int ks = 0; ks < 4; ++ks)
        qf[ks] = *(const bh8*)(Qb + (size_t)(q0 + w * 32 + lq) * DK + ks * 16 + hi * 8);

    // staging source offsets (elems): wave w stages frag f = w per half:
    // K frag: rh = w>>2 (kv 32-half), ks = w&3 (k-slice); V frag analogous.
    const int koff = ((w >> 2) * 32 + lq) * DK + (w & 3) * 16 + hi * 8;
    const int voff = ((w >> 2) * 32 + lq) * SEQ + (w & 3) * 16 + hi * 8;

    f16x oA0 = {}, oA1 = {}, oB0 = {}, oB1 = {};
    float mA = -3.0e38f, lA = 0.f, mB = -3.0e38f, lB = 0.f;

#define STAGE(buf_, half_, kv0_) do {                                         \
    GLL16(Kb + (size_t)(half_) * (2048 * DK) + (size_t)(kv0_) * DK + koff,    \
          lds + (buf_) * 32768 + (half_) * 16384 + w * 1024);                 \
    GLL16(Vb + (half_) * 2048 + (size_t)(kv0_) + voff,                        \
          lds + (buf_) * 32768 + (half_) * 16384 + 8192 + w * 1024);          \
} while (0)

// QK^T of one 64-tile from fragment-major LDS base kb_
#define QKT(kb_, sa0_, sa1_) do {                                             \
    __builtin_amdgcn_s_setprio(1);                                            \
    _Pragma("unroll")                                                         \
    for (int ks_ = 0; ks_ < 4; ++ks_) {                                       \
        bh8 k0_ = *(const bh8*)((kb_) + ks_ * 1024);                          \
        bh8 k1_ = *(const bh8*)((kb_) + (4 + ks_) * 1024);                    \
        sa0_ = MFMA32(k0_, qf[ks_], sa0_);                                    \
        sa1_ = MFMA32(k1_, qf[ks_], sa1_);                                    \
    }                                                                         \
    __builtin_amdgcn_s_setprio(0);                                            \
} while (0)

// R4-proven online softmax + P-pack + PV for one tile; vb_ = V frag base
#define SMPV(kb_, sa0_, sa1_, m_run_, l_run_, o0_, o1_) do {                  \
    float a_ = fmaxf(sa0_[0], sa0_[1]);                                       \
    float b_ = fmaxf(sa1_[0], sa1_[1]);                                       \
    _Pragma("unroll")                                                         \
    for (int r_ = 2; r_ < 16; r_ += 2) {                                      \
        a_ = max3f(a_, sa0_[r_], sa0_[r_ + 1]);                               \
        b_ = max3f(b_, sa1_[r_], sa1_[r_ + 1]);                               \
    }                                                                         \
    const float mx_ = wave_max_pair(fmaxf(a_, b_));                           \
    const bool skip_ = __all(mx_ <= m_run_ + 8.0f);                           \
    float mnew_ = m_run_, corr_ = 1.0f;                                       \
    if (!skip_) {                                                             \
        mnew_ = fmaxf(m_run_, mx_);                                           \
        corr_ = __builtin_amdgcn_exp2f(m_run_ - mnew_);                       \
    }                                                                         \
    uf U0_, U1_; U0_.v = sa0_; U1_.v = sa1_;                                  \
    f2 nm2_; nm2_[0] = -mnew_; nm2_[1] = -mnew_;                              \
    f2 p2_[16];                                                               \
    _Pragma("unroll")                                                         \
    for (int i_ = 0; i_ < 8; ++i_) {                                          \
        f2 t0_ = pk_add(U0_.h[i_], nm2_);                                     \
        f2 t1_ = pk_add(U1_.h[i_], nm2_);                                     \
        f2 e0_, e1_;                                                          \
        e0_[0] = __builtin_amdgcn_exp2f(t0_[0]);                              \
        e0_[1] = __builtin_amdgcn_exp2f(t0_[1]);                              \
        e1_[0] = __builtin_amdgcn_exp2f(t1_[0]);                              \
        e1_[1] = __builtin_amdgcn_exp2f(t1_[1]);                              \
        p2_[i_] = e0_; p2_[8 + i_] = e1_;                                     \
    }                                                                         \
    f2 s0_ = pk_add(p2_[0], p2_[1]),   s1_ = pk_add(p2_[2], p2_[3]);          \
    f2 s2_ = pk_add(p2_[4], p2_[5]),   s3_ = pk_add(p2_[6], p2_[7]);          \
    f2 s4_ = pk_add(p2_[8], p2_[9]),   s5_ = pk_add(p2_[10], p2_[11]);        \
    f2 s6_ = pk_add(p2_[12], p2_[13]), s7_ = pk_add(p2_[14], p2_[15]);        \
    s0_ = pk_add(s0_, s1_); s2_ = pk_add(s2_, s3_);                           \
    s4_ = pk_add(s4_, s5_); s6_ = pk_add(s6_, s7_);                           \
    s0_ = pk_add(s0_, s2_); s4_ = pk_add(s4_, s6_);                           \
    s0_ = pk_add(s0_, s4_);                                                   \
    const float psum_ = wave_sum_pair(s0_[0] + s0_[1]);                       \
    if (!skip_) {                                                             \
        m_run_ = mnew_;                                                       \
        l_run_ = l_run_ * corr_ + psum_;                                      \
        f2 c2_; c2_[0] = corr_; c2_[1] = corr_;                               \
        uf O0_, O1_; O0_.v = o0_; O1_.v = o1_;                                \
        _Pragma("unroll")                                                     \
        for (int i_ = 0; i_ < 8; ++i_) {                                      \
            O0_.h[i_] = pk_mul(O0_.h[i_], c2_);                               \
            O1_.h[i_] = pk_mul(O1_.h[i_], c2_);                               \
        }                                                                     \
        o0_ = O0_.v; o1_ = O1_.v;                                             \
    } else {                                                                  \
        l_run_ += psum_;                                                      \
    }                                                                         \
    bh8 pf_[4];                                                               \
    _Pragma("unroll")                                                         \
    for (int cb_ = 0; cb_ < 2; ++cb_) {                                       \
        unsigned k0_ = cvtpk(p2_[8 * cb_ + 0][0], p2_[8 * cb_ + 0][1]);       \
        unsigned k1_ = cvtpk(p2_[8 * cb_ + 1][0], p2_[8 * cb_ + 1][1]);       \
        unsigned k2_ = cvtpk(p2_[8 * cb_ + 2][0], p2_[8 * cb_ + 2][1]);       \
        unsigned k3_ = cvtpk(p2_[8 * cb_ + 3][0], p2_[8 * cb_ + 3][1]);       \
        unsigned k4_ = cvtpk(p2_[8 * cb_ + 4][0], p2_[8 * cb_ + 4][1]);       \
        unsigned k5_ = cvtpk(p2_[8 * cb_ + 5][0], p2_[8 * cb_ + 5][1]);       \
        unsigned k6_ = cvtpk(p2_[8 * cb_ + 6][0], p2_[8 * cb_ + 6][1]);       \
        unsigned k7_ = cvtpk(p2_[8 * cb_ + 7][0], p2_[8 * cb_ + 7][1]);       \
        plswap(k0_, k2_); plswap(k1_, k3_); plswap(k4_, k6_); plswap(k5_, k7_);\
        union { unsigned u[4]; bh8 v; } f0_, f1_;                             \
        f0_.u[0] = k0_; f0_.u[1] = k1_; f0_.u[2] = k2_; f0_.u[3] = k3_;       \
        f1_.u[0] = k4_; f1_.u[1] = k5_; f1_.u[2] = k6_; f1_.u[3] = k7_;       \
        pf_[cb_ * 2 + 0] = f0_.v;                                             \
        pf_[cb_ * 2 + 1] = f1_.v;                                             \
    }                                                                         \
    const char* vb_ = (kb_) + 8192;                                           \
    __builtin_amdgcn_s_setprio(1);                                            \
    _Pragma("unroll")                                                         \
    for (int ks_ = 0; ks_ < 4; ++ks_) {                                       \
        bh8 v0_ = *(const bh8*)(vb_ + ks_ * 1024);                            \
        bh8 v1_ = *(const bh8*)(vb_ + (4 + ks_) * 1024);                      \
        o0_ = MFMA32(v0_, pf_[ks_], o0_);                                     \
        o1_ = MFMA32(v1_, pf_[ks_], o1_);                                     \
    }                                                                         \
    __builtin_amdgcn_s_setprio(0);                                            \
} while (0)

    STAGE(0, 0, 0);
    STAGE(0, 1, 0);
    __syncthreads();
    int cur = 0;
    const char* myfrag = lds + l * 16;

    for (int t = 0; t < 32; ++t) {          // 32 tiles of 64 per half = 2048
        if (t < 31) {
            STAGE(cur ^ 1, 0, (t + 1) * 64);
            STAGE(cur ^ 1, 1, (t + 1) * 64);
        }

        const char* kbA = myfrag + cur * 32768;            // half A K frags
        const char* kbB = kbA + 16384;                     // half B K frags

        f16x sA0 = {}, sA1 = {}, sB0 = {}, sB1 = {};
        QKT(kbA, sA0, sA1);
        QKT(kbB, sB0, sB1);
        SMPV(kbA, sA0, sA1, mA, lA, oA0, oA1);
        SMPV(kbB, sB0, sB1, mB, lB, oB0, oB1);

        __syncthreads();
        cur ^= 1;
    }
#undef STAGE
#undef QKT
#undef SMPV

    // ---- in-register, in-lane merge of the two kv-half states ----
    const float mt = fmaxf(mA, mB);
    const float cA = __builtin_amdgcn_exp2f(mA - mt);
    const float cB = __builtin_amdgcn_exp2f(mB - mt);
    f16x o0, o1;
    #pragma unroll
    for (int r = 0; r < 16; ++r) {
        o0[r] = oA0[r] * cA + oB0[r] * cB;
        o1[r] = oA1[r] * cA + oB1[r] * cB;
    }
    const float inv = 1.0f / (lA * cA + lB * cB);

    // ---- epilogue: O^T -> row-major via swizzled LDS, coalesced store ----
    char* Tb = lds + w * 4096;     // per-wave 32 q-rows x 128 B (8 waves=32KB)
    #pragma unroll
    for (int db = 0; db < 2; ++db) {
        f16x ov = db ? o1 : o0;
        #pragma unroll
        for (int j = 0; j < 8; ++j) {
            const int r = 2 * j;
            const int d = db * 32 + (r & 3) + 8 * (r >> 2) + 4 * hi;
            unsigned pk = cvtpk(ov[r] * inv, ov[r + 1] * inv);
            *(unsigned*)(Tb + lq * 128 + ((d * 2) ^ ((lq & 7) << 4))) = pk;
        }
    }
    __syncthreads();
    const int b = bh >> 3, h = bh & 7;
    const int row = l >> 1, half = l & 1;
    const int q = q0 + w * 32 + row;
    unsigned short* dst = Ow + ((size_t)b * SEQ + q) * DMODEL + h * DK + half * 32;
    #pragma unroll
    for (int i = 0; i < 4; ++i) {
        const int byte = (half * 64 + i * 16) ^ ((row & 7) << 4);
        uint4 vv = *(const uint4*)(Tb + row * 128 + byte);
        *(uint4*)(dst + i * 8) = vv;
    }
}

// ---------------------------------------------------------------------------
// out = Ow(bf16) @ Wo^T(bf16) -> fp32
// ---------------------------------------------------------------------------
__global__ __launch_bounds__(256) void out_gemm_mfma(
    const unsigned short* __restrict__ Ob,
    const unsigned short* __restrict__ Wob,
    float* __restrict__ out)
{
    const int m0 = blockIdx.x * 128, n0 = blockIdx.y * 128;
    const int tid = threadIdx.x, w = tid >> 6, l = tid & 63;
    const int wr = w >> 1, wc = w & 1;

    __shared__ __align__(16) unsigned short As[128 * 32];
    __shared__ __align__(16) unsigned short Bs[128 * 32];

    f4 acc[4][4] = {};
    const int lrow = l >> 2, lslot = l & 3;

    for (int k0 = 0; k0 < DMODEL; k0 += 32) {
        __syncthreads();
        #pragma unroll
        for (int j = 0; j < 2; ++j) {
            const int row = w * 32 + j * 16 + lrow;
            const int sw = lslot ^ ((row >> 1) & 3);
            GLL16(Ob + (size_t)(m0 + row) * DMODEL + k0 + sw * 8,
                  (char*)As + (w * 32 + j * 16) * 64);
            GLL16(Wob + (size_t)(n0 + row) * DMODEL + k0 + sw * 8,
                  (char*)Bs + (w * 32 + j * 16) * 64);
        }
        __syncthreads();
        bh8 af[4], bg[4];
        #pragma unroll
        for (int mi = 0; mi < 4; ++mi) {
            const int r = wr * 64 + mi * 16 + (l & 15);
            af[mi] = *(const bh8*)((const char*)As + r * 64 +
                                   (((l >> 4) * 16) ^ (((r >> 1) & 3) << 4)));
        }
        #pragma unroll
        for (int ni = 0; ni < 4; ++ni) {
            const int r = wc * 64 + ni * 16 + (l & 15);
            bg[ni] = *(const bh8*)((const char*)Bs + r * 64 +
                                   (((l >> 4) * 16) ^ (((r >> 1) & 3) << 4)));
        }
        #pragma unroll
        for (int mi = 0; mi < 4; ++mi)
            #pragma unroll
            for (int ni = 0; ni < 4; ++ni)
                acc[mi][ni] = MFMA(af[mi], bg[ni], acc[mi][ni]);
    }

    #pragma unroll
    for (int mi = 0; mi < 4; ++mi) {
        #pragma unroll
        for (int rg = 0; rg < 4; ++rg) {
            const int m = m0 + wr * 64 + mi * 16 + (l >> 4) * 4 + rg;
            #pragma unroll
            for (int ni = 0; ni < 4; ++ni) {
                const int n = n0 + wc * 64 + ni * 16 + (l & 15);
                out[(size_t)m * DMODEL + n] = acc[mi][ni][rg];
            }
        }
    }
}

extern "C" void kernel_launch(void* const* d_in, const int* in_sizes, int n_in,
                              void* d_out, int out_size, void* d_ws, size_t ws_size,
                              hipStream_t stream)
{
    const float* x  = (const float*)d_in[0];
    const float* Wq = (const float*)d_in[1];
    const float* Wk = (const float*)d_in[2];
    const float* Wv = (const float*)d_in[3];
    const float* Wo = (const float*)d_in[4];
    float* out = (float*)d_out;

    unsigned short* ws = (unsigned short*)d_ws;
    unsigned short* xb  = ws;                         // 4194304
    unsigned short* Wb  = xb + 4194304;               // 4 x 262144 (q,k,v,o)
    unsigned short* QKV = Wb + 4 * 262144;            // 3 x 4194304
    unsigned short* Vt  = QKV + 3 * 4194304;          // 4194304
    unsigned short* Ow  = Vt + 4194304;               // 4194304
    unsigned short* Qh = QKV;
    unsigned short* Kh = QKV + 4194304;
    unsigned short* Vh = QKV + 2 * 4194304;

    convert_k<<<5120, 256, 0, stream>>>(x, Wq, Wk, Wv, Wo, ws);
    qkv_gemm_mfma<<<dim3(MTOT / 128, DMODEL / 128, 3), 256, 0, stream>>>(xb, Wb, QKV);
    vtrans<<<dim3(SEQ / 64, NBH), 256, 0, stream>>>(Vh, Vt);
    flash_mfma<<<256, 512, 0, stream>>>(Qh, Kh, Vt, Ow);
    out_gemm_mfma<<<dim3(MTOT / 128, DMODEL / 128), 256, 0, stream>>>(
        Ow, Wb + 3 * 262144, out);
}